// Round 2
// baseline (260.311 us; speedup 1.0000x reference)
//
#include <hip/hip_runtime.h>

#define DIM 256

typedef unsigned short u16;
typedef unsigned int u32;
typedef __bf16 bf16x8 __attribute__((ext_vector_type(8)));
typedef float f32x4 __attribute__((ext_vector_type(4)));

__device__ inline float bf2f(u16 u){ union{u32 i; float f;} v; v.i=((u32)u)<<16; return v.f; }
__device__ inline u16 f2bf(float f){
  union{float f; u32 i;} v; v.f=f;
  u32 i=v.i;
  return (u16)((i + 0x7FFFu + ((i>>16)&1u)) >> 16);  // RNE
}

// ---- zero the histogram (ws is poisoned 0xAA every call) ----
__global__ void k_zero(int* __restrict__ p, int n){
  int i = blockIdx.x*blockDim.x + threadIdx.x;
  if(i<n) p[i]=0;
}

// ---- f32 -> bf16 conversion, 4 elements/thread ----
__global__ void k_cvt(const float* __restrict__ in, u16* __restrict__ o, int n4){
  int i = blockIdx.x*blockDim.x + threadIdx.x;
  if(i<n4){
    float4 v = ((const float4*)in)[i];
    ushort4 r; r.x=f2bf(v.x); r.y=f2bf(v.y); r.z=f2bf(v.z); r.w=f2bf(v.w);
    ((ushort4*)o)[i]=r;
  }
}

// ---- in-degree histogram ----
__global__ void k_hist(const int* __restrict__ dst, int E, int* __restrict__ counts){
  int e = blockIdx.x*blockDim.x + threadIdx.x;
  if(e<E) atomicAdd(counts + dst[e], 1);
}

// ---- exclusive scan over 20000 counts (single block) ----
__global__ __launch_bounds__(1024) void k_scan(const int* __restrict__ counts, int n,
                                               int* __restrict__ offsets, int* __restrict__ cursor){
  __shared__ int part[1024];
  int t = threadIdx.x;
  int chunk = (n + 1023) >> 10;
  int s0 = t*chunk; int s1 = min(s0+chunk, n);
  int s = 0;
  for(int i=s0;i<s1;i++) s += counts[i];
  part[t] = s;
  __syncthreads();
  for(int off=1; off<1024; off<<=1){
    int v = (t>=off) ? part[t-off] : 0;
    __syncthreads();
    part[t] += v;
    __syncthreads();
  }
  int run = (t==0) ? 0 : part[t-1];
  for(int i=s0;i<s1;i++){
    offsets[i]=run; cursor[i]=run; run += counts[i];
  }
  if (t==1023) offsets[n] = part[1023];
}

// ---- scatter edge sources into CSR order ----
__global__ void k_scatter(const int* __restrict__ src, const int* __restrict__ dst, int E,
                          int* __restrict__ cursor, int* __restrict__ sorted_src){
  int e = blockIdx.x*blockDim.x + threadIdx.x;
  if(e<E){
    int p = atomicAdd(cursor + dst[e], 1);
    sorted_src[p] = src[e];
  }
}

// ---- per-node mean of gathered bf16 rows; one wave per node, 4 ch/lane ----
__global__ __launch_bounds__(256) void k_aggr(const u16* __restrict__ xb,
    const int* __restrict__ offsets, const int* __restrict__ sorted_src,
    u16* __restrict__ aggr, int n_nodes){
  int wave = threadIdx.x >> 6, lane = threadIdx.x & 63;
  int node = blockIdx.x*4 + wave;
  if(node >= n_nodes) return;
  int b0 = offsets[node], b1 = offsets[node+1];
  int c = lane*4;
  float s0=0.f, s1=0.f, s2=0.f, s3=0.f;
  for(int i=b0;i<b1;i++){
    int sn = sorted_src[i];
    ushort4 v = *(const ushort4*)(xb + (size_t)sn*DIM + c);
    s0 += bf2f(v.x); s1 += bf2f(v.y); s2 += bf2f(v.z); s3 += bf2f(v.w);
  }
  int deg = b1 - b0;
  float inv = 1.0f / (float)(deg > 1 ? deg : 1);
  ushort4 o;
  o.x = f2bf(s0*inv); o.y = f2bf(s1*inv); o.z = f2bf(s2*inv); o.w = f2bf(s3*inv);
  *(ushort4*)(aggr + (size_t)node*DIM + c) = o;
}

// ---- out = aggr @ Wl^T + x @ Wr^T + b  (MFMA 16x16x32 bf16, f32 out) ----
// wave tile: M=16, N=256 (16 col tiles), K=512 fully unrolled.
// A frag:  lane(quad*16+l16) holds A[l16][quad*8 + j], j=0..7 (16B contiguous)
// B frag:  lane holds B[quad*8+j][l16] = W[nt*16+l16][kt*32 + quad*8 + j]
// D:       lane reg r holds D[quad*4+r][l16]
__global__ __launch_bounds__(256) void k_gemm(const u16* __restrict__ xb, const u16* __restrict__ aggr,
    const u16* __restrict__ Wb, const float* __restrict__ br,
    float* __restrict__ out, int n_nodes){
  int wave = threadIdx.x >> 6, lane = threadIdx.x & 63;
  int m0 = blockIdx.x*64 + wave*16;
  if (m0 >= n_nodes) return;
  int quad = lane >> 4, l16 = lane & 15;
  const u16* grow = aggr + (size_t)(m0 + l16)*DIM + quad*8;
  const u16* xrow = xb   + (size_t)(m0 + l16)*DIM + quad*8;
  const u16* wl   = Wb                + (size_t)l16*DIM + quad*8;  // Wl bf16
  const u16* wr   = Wb + DIM*DIM      + (size_t)l16*DIM + quad*8;  // Wr bf16

  f32x4 acc[16];
  #pragma unroll
  for(int i=0;i<16;i++){ f32x4 z = {0.f,0.f,0.f,0.f}; acc[i]=z; }

  #pragma unroll
  for(int kt=0; kt<8; kt++){
    bf16x8 a = *(const bf16x8*)(grow + kt*32);
    #pragma unroll
    for(int nt=0; nt<16; nt++){
      bf16x8 b = *(const bf16x8*)(wl + (size_t)nt*16*DIM + kt*32);
      acc[nt] = __builtin_amdgcn_mfma_f32_16x16x32_bf16(a, b, acc[nt], 0, 0, 0);
    }
  }
  #pragma unroll
  for(int kt=0; kt<8; kt++){
    bf16x8 a = *(const bf16x8*)(xrow + kt*32);
    #pragma unroll
    for(int nt=0; nt<16; nt++){
      bf16x8 b = *(const bf16x8*)(wr + (size_t)nt*16*DIM + kt*32);
      acc[nt] = __builtin_amdgcn_mfma_f32_16x16x32_bf16(a, b, acc[nt], 0, 0, 0);
    }
  }

  #pragma unroll
  for(int nt=0; nt<16; nt++){
    int col = nt*16 + l16;
    float bias = br[col];
    size_t base = (size_t)(m0 + quad*4)*DIM + col;
    out[base]           = acc[nt][0] + bias;
    out[base +   DIM]   = acc[nt][1] + bias;
    out[base + 2*DIM]   = acc[nt][2] + bias;
    out[base + 3*DIM]   = acc[nt][3] + bias;
  }
}

extern "C" void kernel_launch(void* const* d_in, const int* in_sizes, int n_in,
                              void* d_out, int out_size, void* d_ws, size_t ws_size,
                              hipStream_t stream){
  const float* x  = (const float*)d_in[0];
  const int*   ei = (const int*)d_in[1];
  const float* Wl = (const float*)d_in[2];
  const float* Wr = (const float*)d_in[3];
  const float* br = (const float*)d_in[4];
  float* out = (float*)d_out;
  int n_nodes = in_sizes[0] / DIM;   // 20000
  int E = in_sizes[1] / 2;           // 320000
  const int* src = ei;
  const int* dst = ei + E;

  // workspace layout (all 16B aligned): ~21.7 MB total
  int* counts  = (int*)d_ws;                  // [n]
  int* offsets = counts + n_nodes;            // [n+1] (padded to n+8)
  int* cursor  = offsets + (n_nodes + 8);     // [n]
  int* sorted  = cursor + n_nodes;            // [E]
  u16* aggr    = (u16*)(sorted + E);          // [n*DIM] bf16
  u16* xb      = aggr + (size_t)n_nodes*DIM;  // [n*DIM] bf16
  u16* Wb      = xb   + (size_t)n_nodes*DIM;  // [2*DIM*DIM] bf16 (Wl then Wr)

  int nX4 = n_nodes*DIM/4, nW4 = DIM*DIM/4;
  hipLaunchKernelGGL(k_zero,    dim3((n_nodes+255)/256), dim3(256), 0, stream, counts, n_nodes);
  hipLaunchKernelGGL(k_cvt,     dim3((nX4+255)/256),     dim3(256), 0, stream, x,  xb, nX4);
  hipLaunchKernelGGL(k_cvt,     dim3((nW4+255)/256),     dim3(256), 0, stream, Wl, Wb, nW4);
  hipLaunchKernelGGL(k_cvt,     dim3((nW4+255)/256),     dim3(256), 0, stream, Wr, Wb + DIM*DIM, nW4);
  hipLaunchKernelGGL(k_hist,    dim3((E+255)/256),       dim3(256), 0, stream, dst, E, counts);
  hipLaunchKernelGGL(k_scan,    dim3(1),                 dim3(1024),0, stream, counts, n_nodes, offsets, cursor);
  hipLaunchKernelGGL(k_scatter, dim3((E+255)/256),       dim3(256), 0, stream, src, dst, E, cursor, sorted);
  hipLaunchKernelGGL(k_aggr,    dim3((n_nodes+3)/4),     dim3(256), 0, stream, xb, offsets, sorted, aggr, n_nodes);
  hipLaunchKernelGGL(k_gemm,    dim3((n_nodes+63)/64),   dim3(256), 0, stream, xb, aggr, Wb, br, out, n_nodes);
}

// Round 3
// 219.038 us; speedup vs baseline: 1.1884x; 1.1884x over previous
//
#include <hip/hip_runtime.h>

#define DIM 256

typedef unsigned short u16;
typedef unsigned int u32;
typedef __bf16 bf16x8 __attribute__((ext_vector_type(8)));
typedef float f32x4 __attribute__((ext_vector_type(4)));

__device__ inline float bf2f(u16 u){ union{u32 i; float f;} v; v.i=((u32)u)<<16; return v.f; }
__device__ inline u16 f2bf(float f){
  union{float f; u32 i;} v; v.f=f;
  u32 i=v.i;
  return (u16)((i + 0x7FFFu + ((i>>16)&1u)) >> 16);  // RNE
}

// ---- fused prep: zero counts + f32->bf16 cvt of x, Wl, Wr ----
__global__ __launch_bounds__(256) void k_prep(const float* __restrict__ x,
    const float* __restrict__ Wl, const float* __restrict__ Wr,
    u16* __restrict__ xb, u16* __restrict__ Wb, int* __restrict__ counts,
    int n_nodes, int nX4, int nW4){
  int b = blockIdx.x, t = threadIdx.x;
  int zb  = (n_nodes + 255) >> 8;
  int xbk = (nX4 + 255) >> 8;
  int wbk = (nW4 + 255) >> 8;
  if (b < zb){
    int i = b*256 + t; if(i < n_nodes) counts[i] = 0;
  } else if (b < zb + xbk){
    int i = (b - zb)*256 + t;
    if(i < nX4){
      float4 v = ((const float4*)x)[i];
      ushort4 r; r.x=f2bf(v.x); r.y=f2bf(v.y); r.z=f2bf(v.z); r.w=f2bf(v.w);
      ((ushort4*)xb)[i] = r;
    }
  } else if (b < zb + xbk + wbk){
    int i = (b - zb - xbk)*256 + t;
    if(i < nW4){
      float4 v = ((const float4*)Wl)[i];
      ushort4 r; r.x=f2bf(v.x); r.y=f2bf(v.y); r.z=f2bf(v.z); r.w=f2bf(v.w);
      ((ushort4*)Wb)[i] = r;
    }
  } else {
    int i = (b - zb - xbk - wbk)*256 + t;
    if(i < nW4){
      float4 v = ((const float4*)Wr)[i];
      ushort4 r; r.x=f2bf(v.x); r.y=f2bf(v.y); r.z=f2bf(v.z); r.w=f2bf(v.w);
      ((ushort4*)(Wb + DIM*DIM))[i] = r;
    }
  }
}

// ---- in-degree histogram ----
__global__ void k_hist(const int* __restrict__ dst, int E, int* __restrict__ counts){
  int e = blockIdx.x*blockDim.x + threadIdx.x;
  if(e<E) atomicAdd(counts + dst[e], 1);
}

// ---- exclusive scan over 20000 counts (single block) ----
__global__ __launch_bounds__(1024) void k_scan(const int* __restrict__ counts, int n,
                                               int* __restrict__ offsets, int* __restrict__ cursor){
  __shared__ int part[1024];
  int t = threadIdx.x;
  int chunk = (n + 1023) >> 10;
  int s0 = t*chunk; int s1 = min(s0+chunk, n);
  int s = 0;
  for(int i=s0;i<s1;i++) s += counts[i];
  part[t] = s;
  __syncthreads();
  for(int off=1; off<1024; off<<=1){
    int v = (t>=off) ? part[t-off] : 0;
    __syncthreads();
    part[t] += v;
    __syncthreads();
  }
  int run = (t==0) ? 0 : part[t-1];
  for(int i=s0;i<s1;i++){
    offsets[i]=run; cursor[i]=run; run += counts[i];
  }
  if (t==1023) offsets[n] = part[1023];
}

// ---- scatter edge sources into CSR order ----
__global__ void k_scatter(const int* __restrict__ src, const int* __restrict__ dst, int E,
                          int* __restrict__ cursor, int* __restrict__ sorted_src){
  int e = blockIdx.x*blockDim.x + threadIdx.x;
  if(e<E){
    int p = atomicAdd(cursor + dst[e], 1);
    sorted_src[p] = src[e];
  }
}

// ---- per-node mean; one wave per node, 4 ch/lane, degree-loop unrolled x4 ----
__global__ __launch_bounds__(256) void k_aggr(const u16* __restrict__ xb,
    const int* __restrict__ offsets, const int* __restrict__ sorted_src,
    u16* __restrict__ aggr, int n_nodes){
  int wave = threadIdx.x >> 6, lane = threadIdx.x & 63;
  int node = blockIdx.x*4 + wave;
  if(node >= n_nodes) return;
  int b0 = offsets[node], b1 = offsets[node+1];
  const u16* xc = xb + lane*4;
  float s0=0.f, s1=0.f, s2=0.f, s3=0.f;
  int i = b0;
  for(; i+4 <= b1; i+=4){
    int n0=sorted_src[i], n1=sorted_src[i+1], n2=sorted_src[i+2], n3=sorted_src[i+3];
    ushort4 v0 = *(const ushort4*)(xc + (size_t)n0*DIM);
    ushort4 v1 = *(const ushort4*)(xc + (size_t)n1*DIM);
    ushort4 v2 = *(const ushort4*)(xc + (size_t)n2*DIM);
    ushort4 v3 = *(const ushort4*)(xc + (size_t)n3*DIM);
    s0 += bf2f(v0.x); s1 += bf2f(v0.y); s2 += bf2f(v0.z); s3 += bf2f(v0.w);
    s0 += bf2f(v1.x); s1 += bf2f(v1.y); s2 += bf2f(v1.z); s3 += bf2f(v1.w);
    s0 += bf2f(v2.x); s1 += bf2f(v2.y); s2 += bf2f(v2.z); s3 += bf2f(v2.w);
    s0 += bf2f(v3.x); s1 += bf2f(v3.y); s2 += bf2f(v3.z); s3 += bf2f(v3.w);
  }
  for(; i < b1; i++){
    int sn = sorted_src[i];
    ushort4 v = *(const ushort4*)(xc + (size_t)sn*DIM);
    s0 += bf2f(v.x); s1 += bf2f(v.y); s2 += bf2f(v.z); s3 += bf2f(v.w);
  }
  int deg = b1 - b0;
  float inv = 1.0f / (float)(deg > 1 ? deg : 1);
  ushort4 o;
  o.x = f2bf(s0*inv); o.y = f2bf(s1*inv); o.z = f2bf(s2*inv); o.w = f2bf(s3*inv);
  *(ushort4*)(aggr + (size_t)node*DIM + lane*4) = o;
}

// ---- out = aggr @ Wl^T + x @ Wr^T + b  (MFMA 16x16x32 bf16, f32 out) ----
// Block = 4 waves, all on the same 16 rows (m0); wave w covers cols [w*64,(w+1)*64).
// Per wave: M=16, N=64 (4 col tiles), K=512 unrolled -> 64 MFMAs, acc = 16 VGPRs.
// A frag:  lane(quad*16+l16) holds A[l16][quad*8 + j], j=0..7 (16B contiguous)
// B frag:  lane holds B[quad*8+j][l16] = W[nt*16+l16][kt*32 + quad*8 + j]
// D:       lane reg r holds D[quad*4+r][l16]
__global__ __launch_bounds__(256) void k_gemm(const u16* __restrict__ xb, const u16* __restrict__ aggr,
    const u16* __restrict__ Wb, const float* __restrict__ br,
    float* __restrict__ out, int n_nodes){
  int wave = threadIdx.x >> 6, lane = threadIdx.x & 63;
  int m0 = blockIdx.x*16;
  if (m0 >= n_nodes) return;
  int quad = lane >> 4, l16 = lane & 15;
  const u16* grow = aggr + (size_t)(m0 + l16)*DIM + quad*8;
  const u16* xrow = xb   + (size_t)(m0 + l16)*DIM + quad*8;
  // wave's 4 col-tiles start at nt0 = wave*4
  const u16* wl = Wb           + (size_t)(wave*64 + l16)*DIM + quad*8;
  const u16* wr = Wb + DIM*DIM + (size_t)(wave*64 + l16)*DIM + quad*8;

  f32x4 acc[4];
  #pragma unroll
  for(int i=0;i<4;i++){ f32x4 z = {0.f,0.f,0.f,0.f}; acc[i]=z; }

  #pragma unroll
  for(int kt=0; kt<8; kt++){
    bf16x8 a = *(const bf16x8*)(grow + kt*32);
    #pragma unroll
    for(int j=0; j<4; j++){
      bf16x8 b = *(const bf16x8*)(wl + (size_t)j*16*DIM + kt*32);
      acc[j] = __builtin_amdgcn_mfma_f32_16x16x32_bf16(a, b, acc[j], 0, 0, 0);
    }
  }
  #pragma unroll
  for(int kt=0; kt<8; kt++){
    bf16x8 a = *(const bf16x8*)(xrow + kt*32);
    #pragma unroll
    for(int j=0; j<4; j++){
      bf16x8 b = *(const bf16x8*)(wr + (size_t)j*16*DIM + kt*32);
      acc[j] = __builtin_amdgcn_mfma_f32_16x16x32_bf16(a, b, acc[j], 0, 0, 0);
    }
  }

  #pragma unroll
  for(int j=0; j<4; j++){
    int col = wave*64 + j*16 + l16;
    float bias = br[col];
    size_t base = (size_t)(m0 + quad*4)*DIM + col;
    out[base]         = acc[j][0] + bias;
    out[base +   DIM] = acc[j][1] + bias;
    out[base + 2*DIM] = acc[j][2] + bias;
    out[base + 3*DIM] = acc[j][3] + bias;
  }
}

extern "C" void kernel_launch(void* const* d_in, const int* in_sizes, int n_in,
                              void* d_out, int out_size, void* d_ws, size_t ws_size,
                              hipStream_t stream){
  const float* x  = (const float*)d_in[0];
  const int*   ei = (const int*)d_in[1];
  const float* Wl = (const float*)d_in[2];
  const float* Wr = (const float*)d_in[3];
  const float* br = (const float*)d_in[4];
  float* out = (float*)d_out;
  int n_nodes = in_sizes[0] / DIM;   // 20000
  int E = in_sizes[1] / 2;           // 320000
  const int* src = ei;
  const int* dst = ei + E;

  // workspace layout (all 16B aligned): ~21.7 MB total
  int* counts  = (int*)d_ws;                  // [n]
  int* offsets = counts + n_nodes;            // [n+1] (padded to n+8)
  int* cursor  = offsets + (n_nodes + 8);     // [n]
  int* sorted  = cursor + n_nodes;            // [E]
  u16* aggr    = (u16*)(sorted + E);          // [n*DIM] bf16
  u16* xb      = aggr + (size_t)n_nodes*DIM;  // [n*DIM] bf16
  u16* Wb      = xb   + (size_t)n_nodes*DIM;  // [2*DIM*DIM] bf16 (Wl then Wr)

  int nX4 = n_nodes*DIM/4, nW4 = DIM*DIM/4;
  int prep_blocks = ((n_nodes+255)>>8) + ((nX4+255)>>8) + 2*((nW4+255)>>8);
  hipLaunchKernelGGL(k_prep,    dim3(prep_blocks),       dim3(256), 0, stream,
                     x, Wl, Wr, xb, Wb, counts, n_nodes, nX4, nW4);
  hipLaunchKernelGGL(k_hist,    dim3((E+255)/256),       dim3(256), 0, stream, dst, E, counts);
  hipLaunchKernelGGL(k_scan,    dim3(1),                 dim3(1024),0, stream, counts, n_nodes, offsets, cursor);
  hipLaunchKernelGGL(k_scatter, dim3((E+255)/256),       dim3(256), 0, stream, src, dst, E, cursor, sorted);
  hipLaunchKernelGGL(k_aggr,    dim3((n_nodes+3)/4),     dim3(256), 0, stream, xb, offsets, sorted, aggr, n_nodes);
  hipLaunchKernelGGL(k_gemm,    dim3(n_nodes/16),        dim3(256), 0, stream, xb, aggr, Wb, br, out, n_nodes);
}

// Round 4
// 212.493 us; speedup vs baseline: 1.2250x; 1.0308x over previous
//
#include <hip/hip_runtime.h>

#define DIM 256
#define KCAT 512

typedef unsigned short u16;
typedef unsigned int u32;
typedef __bf16 bf16x8 __attribute__((ext_vector_type(8)));
typedef float f32x4 __attribute__((ext_vector_type(4)));

__device__ inline float bf2f(u16 u){ union{u32 i; float f;} v; v.i=((u32)u)<<16; return v.f; }
__device__ inline u16 f2bf(float f){
  union{float f; u32 i;} v; v.f=f;
  u32 i=v.i;
  return (u16)((i + 0x7FFFu + ((i>>16)&1u)) >> 16);  // RNE
}

// ---- fused prep: zero counts + f32->bf16 cvt into concatenated layouts ----
// acat[node][0:256] = (aggr, written later)   acat[node][256:512] = x (bf16)
// Wcat[col][0:256]  = Wl[col]                 Wcat[col][256:512]  = Wr[col]
__global__ __launch_bounds__(256) void k_prep(const float* __restrict__ x,
    const float* __restrict__ Wl, const float* __restrict__ Wr,
    u16* __restrict__ acat, u16* __restrict__ Wcat, int* __restrict__ counts,
    int n_nodes, int nX4, int nW4){
  int b = blockIdx.x, t = threadIdx.x;
  int zb  = (n_nodes + 255) >> 8;
  int xbk = (nX4 + 255) >> 8;
  int wbk = (nW4 + 255) >> 8;
  if (b < zb){
    int i = b*256 + t; if(i < n_nodes) counts[i] = 0;
  } else if (b < zb + xbk){
    int i = (b - zb)*256 + t;
    if(i < nX4){
      float4 v = ((const float4*)x)[i];
      ushort4 r; r.x=f2bf(v.x); r.y=f2bf(v.y); r.z=f2bf(v.z); r.w=f2bf(v.w);
      int node = i >> 6, k4 = i & 63;
      ((ushort4*)acat)[node*128 + 64 + k4] = r;
    }
  } else if (b < zb + xbk + wbk){
    int i = (b - zb - xbk)*256 + t;
    if(i < nW4){
      float4 v = ((const float4*)Wl)[i];
      ushort4 r; r.x=f2bf(v.x); r.y=f2bf(v.y); r.z=f2bf(v.z); r.w=f2bf(v.w);
      int c = i >> 6, k4 = i & 63;
      ((ushort4*)Wcat)[c*128 + k4] = r;
    }
  } else {
    int i = (b - zb - xbk - wbk)*256 + t;
    if(i < nW4){
      float4 v = ((const float4*)Wr)[i];
      ushort4 r; r.x=f2bf(v.x); r.y=f2bf(v.y); r.z=f2bf(v.z); r.w=f2bf(v.w);
      int c = i >> 6, k4 = i & 63;
      ((ushort4*)Wcat)[c*128 + 64 + k4] = r;
    }
  }
}

// ---- in-degree histogram, 4 edges/thread ----
__global__ void k_hist(const int* __restrict__ dst, int E4, int* __restrict__ counts){
  int e = blockIdx.x*blockDim.x + threadIdx.x;
  if(e<E4){
    int4 d = ((const int4*)dst)[e];
    atomicAdd(counts + d.x, 1);
    atomicAdd(counts + d.y, 1);
    atomicAdd(counts + d.z, 1);
    atomicAdd(counts + d.w, 1);
  }
}

// ---- exclusive scan over 20000 counts (single block) ----
__global__ __launch_bounds__(1024) void k_scan(const int* __restrict__ counts, int n,
                                               int* __restrict__ offsets, int* __restrict__ cursor){
  __shared__ int part[1024];
  int t = threadIdx.x;
  int chunk = (n + 1023) >> 10;
  int s0 = t*chunk; int s1 = min(s0+chunk, n);
  int s = 0;
  for(int i=s0;i<s1;i++) s += counts[i];
  part[t] = s;
  __syncthreads();
  for(int off=1; off<1024; off<<=1){
    int v = (t>=off) ? part[t-off] : 0;
    __syncthreads();
    part[t] += v;
    __syncthreads();
  }
  int run = (t==0) ? 0 : part[t-1];
  for(int i=s0;i<s1;i++){
    offsets[i]=run; cursor[i]=run; run += counts[i];
  }
  if (t==1023) offsets[n] = part[1023];
}

// ---- scatter edge sources into CSR order, 4 edges/thread ----
__global__ void k_scatter(const int* __restrict__ src, const int* __restrict__ dst, int E4,
                          int* __restrict__ cursor, int* __restrict__ sorted_src){
  int e = blockIdx.x*blockDim.x + threadIdx.x;
  if(e<E4){
    int4 s = ((const int4*)src)[e];
    int4 d = ((const int4*)dst)[e];
    sorted_src[atomicAdd(cursor + d.x, 1)] = s.x;
    sorted_src[atomicAdd(cursor + d.y, 1)] = s.y;
    sorted_src[atomicAdd(cursor + d.z, 1)] = s.z;
    sorted_src[atomicAdd(cursor + d.w, 1)] = s.w;
  }
}

// ---- per-node mean; one wave/node, 4 ch/lane, degree-loop unrolled x8 ----
__global__ __launch_bounds__(256) void k_aggr(u16* __restrict__ acat,
    const int* __restrict__ offsets, const int* __restrict__ sorted_src, int n_nodes){
  int wave = threadIdx.x >> 6, lane = threadIdx.x & 63;
  int node = blockIdx.x*4 + wave;
  if(node >= n_nodes) return;
  int b0 = offsets[node], b1 = offsets[node+1];
  const u16* xc = acat + 256 + lane*4;   // x half of acat rows
  float s0=0.f, s1=0.f, s2=0.f, s3=0.f;
  int i = b0;
  for(; i+8 <= b1; i+=8){
    int idx[8];
    #pragma unroll
    for(int u=0;u<8;u++) idx[u] = sorted_src[i+u];
    ushort4 v[8];
    #pragma unroll
    for(int u=0;u<8;u++) v[u] = *(const ushort4*)(xc + (size_t)idx[u]*KCAT);
    #pragma unroll
    for(int u=0;u<8;u++){
      s0 += bf2f(v[u].x); s1 += bf2f(v[u].y); s2 += bf2f(v[u].z); s3 += bf2f(v[u].w);
    }
  }
  for(; i < b1; i++){
    int sn = sorted_src[i];
    ushort4 v = *(const ushort4*)(xc + (size_t)sn*KCAT);
    s0 += bf2f(v.x); s1 += bf2f(v.y); s2 += bf2f(v.z); s3 += bf2f(v.w);
  }
  int deg = b1 - b0;
  float inv = 1.0f / (float)(deg > 1 ? deg : 1);
  ushort4 o;
  o.x = f2bf(s0*inv); o.y = f2bf(s1*inv); o.z = f2bf(s2*inv); o.w = f2bf(s3*inv);
  *(ushort4*)(acat + (size_t)node*KCAT + lane*4) = o;
}

// ---- out = acat @ Wcat^T + b  (M=20000, N=256, K=512; MFMA 16x16x32 bf16) ----
// Wave owns 32 cols (col-group cg = blockIdx&7 gives base, wave j in {0,1} tiles):
// B-frags (2 tiles x 16 kt = 128 VGPRs) loaded ONCE, then loop 4 M-tiles:
// 16 independent A-loads + 32 MFMAs per tile.
// A frag: lane(quad*16+l16) holds A[l16][kt*32+quad*8+j]  (16B contiguous)
// B frag: lane holds W[col=ct*16+l16][kt*32+quad*8+j]     (16B contiguous)
// D:      lane reg r holds D[quad*4+r][l16]
__global__ __launch_bounds__(256, 2) void k_gemm(const u16* __restrict__ acat,
    const u16* __restrict__ Wcat, const float* __restrict__ br,
    float* __restrict__ out, int n_nodes){
  int wave = threadIdx.x >> 6, lane = threadIdx.x & 63;
  int quad = lane >> 4, l16 = lane & 15;
  int cg = blockIdx.x & 7;                      // 8 col-groups of 32 cols
  int mt0 = (blockIdx.x >> 3)*16 + wave*4;      // 4 M-tiles per wave
  int Mtiles = n_nodes >> 4;

  const u16* wbase = Wcat + (size_t)(cg*32 + l16)*KCAT + quad*8;
  bf16x8 B[2][16];
  #pragma unroll
  for(int j=0;j<2;j++)
    #pragma unroll
    for(int kt=0;kt<16;kt++)
      B[j][kt] = *(const bf16x8*)(wbase + (size_t)j*16*KCAT + kt*32);

  int col0 = cg*32 + l16, col1 = col0 + 16;
  float bi0 = br[col0], bi1 = br[col1];

  for(int t=0; t<4; t++){
    int mt = mt0 + t;
    if (mt >= Mtiles) break;
    const u16* arow = acat + (size_t)(mt*16 + l16)*KCAT + quad*8;
    f32x4 acc0 = {0.f,0.f,0.f,0.f}, acc1 = {0.f,0.f,0.f,0.f};
    #pragma unroll
    for(int kt=0;kt<16;kt++){
      bf16x8 a = *(const bf16x8*)(arow + kt*32);
      acc0 = __builtin_amdgcn_mfma_f32_16x16x32_bf16(a, B[0][kt], acc0, 0, 0, 0);
      acc1 = __builtin_amdgcn_mfma_f32_16x16x32_bf16(a, B[1][kt], acc1, 0, 0, 0);
    }
    size_t base = (size_t)(mt*16 + quad*4)*DIM;
    #pragma unroll
    for(int r=0;r<4;r++){
      out[base + (size_t)r*DIM + col0] = acc0[r] + bi0;
      out[base + (size_t)r*DIM + col1] = acc1[r] + bi1;
    }
  }
}

extern "C" void kernel_launch(void* const* d_in, const int* in_sizes, int n_in,
                              void* d_out, int out_size, void* d_ws, size_t ws_size,
                              hipStream_t stream){
  const float* x  = (const float*)d_in[0];
  const int*   ei = (const int*)d_in[1];
  const float* Wl = (const float*)d_in[2];
  const float* Wr = (const float*)d_in[3];
  const float* br = (const float*)d_in[4];
  float* out = (float*)d_out;
  int n_nodes = in_sizes[0] / DIM;   // 20000
  int E = in_sizes[1] / 2;           // 320000
  const int* src = ei;
  const int* dst = ei + E;

  // workspace layout (all 16B aligned): ~22.3 MB
  int* counts  = (int*)d_ws;                   // [n]
  int* offsets = counts + n_nodes;             // [n+1] (padded to n+8)
  int* cursor  = offsets + (n_nodes + 8);      // [n]
  int* sorted  = cursor + n_nodes;             // [E]
  u16* acat    = (u16*)(sorted + E);           // [n*512] bf16: [aggr | x]
  u16* Wcat    = acat + (size_t)n_nodes*KCAT;  // [256*512] bf16: [Wl | Wr]

  int nX4 = n_nodes*DIM/4, nW4 = DIM*DIM/4;
  int prep_blocks = ((n_nodes+255)>>8) + ((nX4+255)>>8) + 2*((nW4+255)>>8);
  int Mtiles = n_nodes >> 4;                   // 1250
  int mblocks = (Mtiles + 15) >> 4;            // 79 (16 tiles per block: 4 waves x 4)

  hipLaunchKernelGGL(k_prep,    dim3(prep_blocks),       dim3(256), 0, stream,
                     x, Wl, Wr, acat, Wcat, counts, n_nodes, nX4, nW4);
  hipLaunchKernelGGL(k_hist,    dim3((E/4+255)/256),     dim3(256), 0, stream, dst, E/4, counts);
  hipLaunchKernelGGL(k_scan,    dim3(1),                 dim3(1024),0, stream, counts, n_nodes, offsets, cursor);
  hipLaunchKernelGGL(k_scatter, dim3((E/4+255)/256),     dim3(256), 0, stream, src, dst, E/4, cursor, sorted);
  hipLaunchKernelGGL(k_aggr,    dim3((n_nodes+3)/4),     dim3(256), 0, stream, acat, offsets, sorted, n_nodes);
  hipLaunchKernelGGL(k_gemm,    dim3(mblocks*8),         dim3(256), 0, stream, acat, Wcat, br, out, n_nodes);
}

// Round 5
// 180.672 us; speedup vs baseline: 1.4408x; 1.1761x over previous
//
#include <hip/hip_runtime.h>

#define DIM 256
#define KCAT 512

typedef unsigned short u16;
typedef unsigned int u32;
typedef __bf16 bf16x8 __attribute__((ext_vector_type(8)));
typedef float f32x4 __attribute__((ext_vector_type(4)));

__device__ inline float bf2f(u16 u){ union{u32 i; float f;} v; v.i=((u32)u)<<16; return v.f; }
__device__ inline u16 f2bf(float f){
  union{float f; u32 i;} v; v.f=f;
  u32 i=v.i;
  return (u16)((i + 0x7FFFu + ((i>>16)&1u)) >> 16);  // RNE
}
__device__ inline ushort4 cvt4(float4 v){
  ushort4 r; r.x=f2bf(v.x); r.y=f2bf(v.y); r.z=f2bf(v.z); r.w=f2bf(v.w); return r;
}

// ---- 1: zero in-degree counts ----
__global__ void k_zero(int* __restrict__ p, int n){
  int i = blockIdx.x*blockDim.x + threadIdx.x;
  if(i<n) p[i]=0;
}

// ---- 2: in-degree histogram (int4 edges) + Wl/Wr -> Wcat bf16 cvt ----
// Wcat[col][0:256] = Wl[col][:], Wcat[col][256:512] = Wr[col][:]
__global__ __launch_bounds__(256) void k_hist_cvtw(const int* __restrict__ dst, int E,
    int* __restrict__ counts, const float* __restrict__ Wl, const float* __restrict__ Wr,
    u16* __restrict__ Wcat, int nW4){
  int E4 = E >> 2;
  int hb = (E4 + 255) >> 8;
  int b = blockIdx.x, t = threadIdx.x;
  if (b < hb){
    int e = b*256 + t;
    if(e < E4){
      int4 d = ((const int4*)dst)[e];
      atomicAdd(counts + d.x, 1);
      atomicAdd(counts + d.y, 1);
      atomicAdd(counts + d.z, 1);
      atomicAdd(counts + d.w, 1);
    }
    if (b==0 && t==0){
      for(int e2 = E4*4; e2 < E; e2++) atomicAdd(counts + dst[e2], 1);
    }
  } else {
    int i = (b - hb)*256 + t;
    if (i < 2*nW4){
      int sel = (i >= nW4);
      int ii = sel ? i - nW4 : i;
      float4 v = sel ? ((const float4*)Wr)[ii] : ((const float4*)Wl)[ii];
      int col = ii >> 6, k4 = ii & 63;      // 64 float4 per 256-f32 row
      ((ushort4*)Wcat)[col*128 + sel*64 + k4] = cvt4(v);
    }
  }
}

// ---- 3: exclusive scan over counts (single block, int4 vectorized) ----
// Requires n % 4 == 0 handled via guards; n=20000 -> threads 0..999 cover 20 each.
__global__ __launch_bounds__(1024) void k_scan(const int* __restrict__ counts, int n,
                                               int* __restrict__ offsets, int* __restrict__ cursor){
  __shared__ int part[1024];
  int t = threadIdx.x;
  int chunk = ((n + 1023) >> 10 + 0) ; // placeholder, recomputed below
  chunk = (n + 1023) >> 10;
  chunk = (chunk + 3) & ~3;            // multiple of 4 for int4
  int s0 = t*chunk;
  int4 c[16];                          // chunk<=64 supported
  int nv = 0;
  int s = 0;
  if (s0 < n){
    int lim = min(s0 + chunk, n);
    for(int i = s0; i < lim; i += 4){
      c[nv] = ((const int4*)(counts + i))[0];
      s += c[nv].x + c[nv].y + c[nv].z + c[nv].w;
      nv++;
    }
  }
  part[t] = s;
  __syncthreads();
  for(int off=1; off<1024; off<<=1){
    int v = (t>=off) ? part[t-off] : 0;
    __syncthreads();
    part[t] += v;
    __syncthreads();
  }
  if (s0 < n){
    int run = (t==0) ? 0 : part[t-1];
    for(int u=0; u<nv; u++){
      int4 o;
      o.x = run; run += c[u].x;
      o.y = run; run += c[u].y;
      o.z = run; run += c[u].z;
      o.w = run; run += c[u].w;
      ((int4*)(offsets + s0 + 4*u))[0] = o;
      ((int4*)(cursor  + s0 + 4*u))[0] = o;
    }
  }
  if (t == 1023) offsets[n] = part[1023];
}

// ---- 4: scatter edges into CSR order (int4) + x -> xb bf16 cvt ----
__global__ __launch_bounds__(256) void k_scatter_cvtx(const int* __restrict__ src,
    const int* __restrict__ dst, int E, int* __restrict__ cursor, int* __restrict__ sorted_src,
    const float* __restrict__ x, u16* __restrict__ xb, int nX4){
  int E4 = E >> 2;
  int sb = (E4 + 255) >> 8;
  int b = blockIdx.x, t = threadIdx.x;
  if (b < sb){
    int e = b*256 + t;
    if(e < E4){
      int4 s = ((const int4*)src)[e];
      int4 d = ((const int4*)dst)[e];
      sorted_src[atomicAdd(cursor + d.x, 1)] = s.x;
      sorted_src[atomicAdd(cursor + d.y, 1)] = s.y;
      sorted_src[atomicAdd(cursor + d.z, 1)] = s.z;
      sorted_src[atomicAdd(cursor + d.w, 1)] = s.w;
    }
    if (b==0 && t==0){
      for(int e2 = E4*4; e2 < E; e2++)
        sorted_src[atomicAdd(cursor + dst[e2], 1)] = src[e2];
    }
  } else {
    int i = (b - sb)*256 + t;
    if (i < nX4) ((ushort4*)xb)[i] = cvt4(((const float4*)x)[i]);
  }
}

// ---- 5: per-node mean; one wave/node, 4 ch/lane, degree-loop unrolled x8 ----
__global__ __launch_bounds__(256) void k_aggr(const u16* __restrict__ xb,
    const int* __restrict__ offsets, const int* __restrict__ sorted_src,
    u16* __restrict__ aggr, int n_nodes){
  int wave = threadIdx.x >> 6, lane = threadIdx.x & 63;
  int node = blockIdx.x*4 + wave;
  if(node >= n_nodes) return;
  int b0 = offsets[node], b1 = offsets[node+1];
  const u16* xc = xb + lane*4;
  float s0=0.f, s1=0.f, s2=0.f, s3=0.f;
  int i = b0;
  for(; i+8 <= b1; i+=8){
    int idx[8];
    #pragma unroll
    for(int u=0;u<8;u++) idx[u] = sorted_src[i+u];
    ushort4 v[8];
    #pragma unroll
    for(int u=0;u<8;u++) v[u] = *(const ushort4*)(xc + (size_t)idx[u]*DIM);
    #pragma unroll
    for(int u=0;u<8;u++){
      s0 += bf2f(v[u].x); s1 += bf2f(v[u].y); s2 += bf2f(v[u].z); s3 += bf2f(v[u].w);
    }
  }
  for(; i < b1; i++){
    int sn = sorted_src[i];
    ushort4 v = *(const ushort4*)(xc + (size_t)sn*DIM);
    s0 += bf2f(v.x); s1 += bf2f(v.y); s2 += bf2f(v.z); s3 += bf2f(v.w);
  }
  int deg = b1 - b0;
  float inv = 1.0f / (float)(deg > 1 ? deg : 1);
  ushort4 o;
  o.x = f2bf(s0*inv); o.y = f2bf(s1*inv); o.z = f2bf(s2*inv); o.w = f2bf(s3*inv);
  *(ushort4*)(aggr + (size_t)node*DIM + lane*4) = o;
}

// ---- 6: out = aggr @ Wl^T + x @ Wr^T + b  (MFMA 16x16x32 bf16) ----
// Block = 4 waves covering the SAME 5 M-tiles, 4 DIFFERENT 32-col groups
// -> A-loads coincide across waves (L1/L2 hits), L3 A-traffic /4.
// Per wave: B-frags for 32 cols x K=512 (128 VGPRs) loaded once; then
// 5 tiles x (16 independent A-loads + 32 MFMAs + 8 stores).
// A frag: lane(quad*16+l16) holds A[l16][kt*32+quad*8+j] (16B contiguous)
// B frag: lane holds W[col=ct*16+l16][kt*32+quad*8+j]
// D:      lane reg r holds D[quad*4+r][l16]
__global__ __launch_bounds__(256, 2) void k_gemm(const u16* __restrict__ aggr,
    const u16* __restrict__ xb, const u16* __restrict__ Wcat, const float* __restrict__ br,
    float* __restrict__ out, int Mtiles){
  int wave = threadIdx.x >> 6, lane = threadIdx.x & 63;
  int quad = lane >> 4, l16 = lane & 15;
  int half = blockIdx.x & 1;             // cols [half*128, half*128+128)
  int mb   = blockIdx.x >> 1;            // 5 M-tiles per block
  int colbase = half*128 + wave*32;

  const u16* wbase = Wcat + (size_t)(colbase + l16)*KCAT + quad*8;
  bf16x8 B[2][16];
  #pragma unroll
  for(int ct=0; ct<2; ct++)
    #pragma unroll
    for(int kt=0; kt<16; kt++)
      B[ct][kt] = *(const bf16x8*)(wbase + (size_t)ct*16*KCAT + kt*32);

  int col0 = colbase + l16, col1 = col0 + 16;
  float bi0 = br[col0], bi1 = br[col1];

  #pragma unroll
  for(int tt=0; tt<5; tt++){
    int mt = mb*5 + tt;
    if (mt >= Mtiles) break;
    const u16* arowA = aggr + (size_t)(mt*16 + l16)*DIM + quad*8;
    const u16* arowX = xb   + (size_t)(mt*16 + l16)*DIM + quad*8;
    f32x4 acc0 = {0.f,0.f,0.f,0.f}, acc1 = {0.f,0.f,0.f,0.f};
    #pragma unroll
    for(int kt=0; kt<8; kt++){
      bf16x8 a = *(const bf16x8*)(arowA + kt*32);
      acc0 = __builtin_amdgcn_mfma_f32_16x16x32_bf16(a, B[0][kt], acc0, 0, 0, 0);
      acc1 = __builtin_amdgcn_mfma_f32_16x16x32_bf16(a, B[1][kt], acc1, 0, 0, 0);
    }
    #pragma unroll
    for(int kt=0; kt<8; kt++){
      bf16x8 a = *(const bf16x8*)(arowX + kt*32);
      acc0 = __builtin_amdgcn_mfma_f32_16x16x32_bf16(a, B[0][kt+8], acc0, 0, 0, 0);
      acc1 = __builtin_amdgcn_mfma_f32_16x16x32_bf16(a, B[1][kt+8], acc1, 0, 0, 0);
    }
    size_t base = (size_t)(mt*16 + quad*4)*DIM;
    #pragma unroll
    for(int r=0;r<4;r++){
      out[base + (size_t)r*DIM + col0] = acc0[r] + bi0;
      out[base + (size_t)r*DIM + col1] = acc1[r] + bi1;
    }
  }
}

extern "C" void kernel_launch(void* const* d_in, const int* in_sizes, int n_in,
                              void* d_out, int out_size, void* d_ws, size_t ws_size,
                              hipStream_t stream){
  const float* x  = (const float*)d_in[0];
  const int*   ei = (const int*)d_in[1];
  const float* Wl = (const float*)d_in[2];
  const float* Wr = (const float*)d_in[3];
  const float* br = (const float*)d_in[4];
  float* out = (float*)d_out;
  int n_nodes = in_sizes[0] / DIM;   // 20000
  int E = in_sizes[1] / 2;           // 320000
  const int* src = ei;
  const int* dst = ei + E;

  // workspace layout (16B aligned sections): ~22.3 MB
  int* counts  = (int*)d_ws;                   // [n]
  int* offsets = counts + n_nodes;             // [n+1] (padded to n+8)
  int* cursor  = offsets + (n_nodes + 8);      // [n]
  int* sorted  = cursor + n_nodes;             // [E]
  u16* xb      = (u16*)(sorted + E);           // [n*DIM] bf16
  u16* aggr    = xb + (size_t)n_nodes*DIM;     // [n*DIM] bf16
  u16* Wcat    = aggr + (size_t)n_nodes*DIM;   // [256*512] bf16: [Wl | Wr] per col

  int nX4 = n_nodes*DIM/4, nW4 = DIM*DIM/4;
  int E4 = E >> 2;
  int hist_blocks = ((E4+255)>>8) + ((2*nW4+255)>>8);
  int scat_blocks = ((E4+255)>>8) + ((nX4+255)>>8);
  int Mtiles = n_nodes >> 4;                   // 1250
  int gemm_blocks = ((Mtiles + 4)/5) * 2;      // 500

  hipLaunchKernelGGL(k_zero,         dim3((n_nodes+255)/256), dim3(256), 0, stream, counts, n_nodes);
  hipLaunchKernelGGL(k_hist_cvtw,    dim3(hist_blocks),       dim3(256), 0, stream,
                     dst, E, counts, Wl, Wr, Wcat, nW4);
  hipLaunchKernelGGL(k_scan,         dim3(1),                 dim3(1024),0, stream,
                     counts, n_nodes, offsets, cursor);
  hipLaunchKernelGGL(k_scatter_cvtx, dim3(scat_blocks),       dim3(256), 0, stream,
                     src, dst, E, cursor, sorted, x, xb, nX4);
  hipLaunchKernelGGL(k_aggr,         dim3((n_nodes+3)/4),     dim3(256), 0, stream,
                     xb, offsets, sorted, aggr, n_nodes);
  hipLaunchKernelGGL(k_gemm,         dim3(gemm_blocks),       dim3(256), 0, stream,
                     aggr, xb, Wcat, br, out, Mtiles);
}

// Round 6
// 171.190 us; speedup vs baseline: 1.5206x; 1.0554x over previous
//
#include <hip/hip_runtime.h>

#define DIM 256
#define KCAT 512

typedef unsigned short u16;
typedef unsigned int u32;
typedef __bf16 bf16x8 __attribute__((ext_vector_type(8)));
typedef float f32x4 __attribute__((ext_vector_type(4)));

__device__ inline float bf2f(u16 u){ union{u32 i; float f;} v; v.i=((u32)u)<<16; return v.f; }
__device__ inline u16 f2bf(float f){
  union{float f; u32 i;} v; v.f=f;
  u32 i=v.i;
  return (u16)((i + 0x7FFFu + ((i>>16)&1u)) >> 16);  // RNE
}
__device__ inline ushort4 cvt4(float4 v){
  ushort4 r; r.x=f2bf(v.x); r.y=f2bf(v.y); r.z=f2bf(v.z); r.w=f2bf(v.w); return r;
}

// ---- 1: zero in-degree counts ----
__global__ void k_zero(int* __restrict__ p, int n){
  int i = blockIdx.x*blockDim.x + threadIdx.x;
  if(i<n) p[i]=0;
}

// ---- 2: in-degree histogram (int4 edges) + Wl/Wr -> Wcat bf16 cvt ----
// Wcat[col][0:256] = Wl[col][:], Wcat[col][256:512] = Wr[col][:]
__global__ __launch_bounds__(256) void k_hist_cvtw(const int* __restrict__ dst, int E,
    int* __restrict__ counts, const float* __restrict__ Wl, const float* __restrict__ Wr,
    u16* __restrict__ Wcat, int nW4){
  int E4 = E >> 2;
  int hb = (E4 + 255) >> 8;
  int b = blockIdx.x, t = threadIdx.x;
  if (b < hb){
    int e = b*256 + t;
    if(e < E4){
      int4 d = ((const int4*)dst)[e];
      atomicAdd(counts + d.x, 1);
      atomicAdd(counts + d.y, 1);
      atomicAdd(counts + d.z, 1);
      atomicAdd(counts + d.w, 1);
    }
    if (b==0 && t==0){
      for(int e2 = E4*4; e2 < E; e2++) atomicAdd(counts + dst[e2], 1);
    }
  } else {
    int i = (b - hb)*256 + t;
    if (i < 2*nW4){
      int sel = (i >= nW4);
      int ii = sel ? i - nW4 : i;
      float4 v = sel ? ((const float4*)Wr)[ii] : ((const float4*)Wl)[ii];
      int col = ii >> 6, k4 = ii & 63;      // 64 float4 per 256-f32 row
      ((ushort4*)Wcat)[col*128 + sel*64 + k4] = cvt4(v);
    }
  }
}

// ---- 3: exclusive scan over counts (single block, 20 elem/thread, STATIC regs) ----
// Wave-shuffle inclusive scan (no barriers) + 16 wave partials (2 barriers).
__global__ __launch_bounds__(1024) void k_scan(const int* __restrict__ counts, int n,
                                               int* __restrict__ offsets, int* __restrict__ cursor){
  __shared__ int wsum[16];
  int t = threadIdx.x;
  int s0 = t*20;
  int4 c[5];
  int s = 0;
  #pragma unroll
  for(int u=0; u<5; u++){
    int i = s0 + 4*u;
    int4 cv = {0,0,0,0};
    if (i + 3 < n){
      cv = *(const int4*)(counts + i);
    } else {
      if (i   < n) cv.x = counts[i];
      if (i+1 < n) cv.y = counts[i+1];
      if (i+2 < n) cv.z = counts[i+2];
      if (i+3 < n) cv.w = counts[i+3];
    }
    c[u] = cv;
    s += cv.x + cv.y + cv.z + cv.w;
  }
  // inclusive scan of s within each wave (all 1024 threads active)
  int lane = t & 63, wid = t >> 6;
  int sc = s;
  #pragma unroll
  for(int off=1; off<64; off<<=1){
    int v = __shfl_up(sc, off, 64);
    if (lane >= off) sc += v;
  }
  if (lane == 63) wsum[wid] = sc;
  __syncthreads();
  if (t == 0){
    int run = 0;
    #pragma unroll
    for(int w=0; w<16; w++){ int v = wsum[w]; wsum[w] = run; run += v; }
  }
  __syncthreads();
  int run = wsum[wid] + (sc - s);   // exclusive prefix for this thread's first element
  #pragma unroll
  for(int u=0; u<5; u++){
    int i = s0 + 4*u;
    int4 o;
    o.x = run; run += c[u].x;
    o.y = run; run += c[u].y;
    o.z = run; run += c[u].z;
    o.w = run; run += c[u].w;
    if (i + 3 < n){
      *(int4*)(offsets + i) = o;
      *(int4*)(cursor  + i) = o;
    } else {
      if (i   < n){ offsets[i]   = o.x; cursor[i]   = o.x; }
      if (i+1 < n){ offsets[i+1] = o.y; cursor[i+1] = o.y; }
      if (i+2 < n){ offsets[i+2] = o.z; cursor[i+2] = o.z; }
      if (i+3 < n){ offsets[i+3] = o.w; cursor[i+3] = o.w; }
    }
  }
  if (t == 1023) offsets[n] = wsum[15] + sc;   // grand total (s==0 on inactive tail threads)
}

// ---- 4: scatter edges into CSR order (int4) + x -> xb bf16 cvt ----
__global__ __launch_bounds__(256) void k_scatter_cvtx(const int* __restrict__ src,
    const int* __restrict__ dst, int E, int* __restrict__ cursor, int* __restrict__ sorted_src,
    const float* __restrict__ x, u16* __restrict__ xb, int nX4){
  int E4 = E >> 2;
  int sb = (E4 + 255) >> 8;
  int b = blockIdx.x, t = threadIdx.x;
  if (b < sb){
    int e = b*256 + t;
    if(e < E4){
      int4 s = ((const int4*)src)[e];
      int4 d = ((const int4*)dst)[e];
      sorted_src[atomicAdd(cursor + d.x, 1)] = s.x;
      sorted_src[atomicAdd(cursor + d.y, 1)] = s.y;
      sorted_src[atomicAdd(cursor + d.z, 1)] = s.z;
      sorted_src[atomicAdd(cursor + d.w, 1)] = s.w;
    }
    if (b==0 && t==0){
      for(int e2 = E4*4; e2 < E; e2++)
        sorted_src[atomicAdd(cursor + dst[e2], 1)] = src[e2];
    }
  } else {
    int i = (b - sb)*256 + t;
    if (i < nX4) ((ushort4*)xb)[i] = cvt4(((const float4*)x)[i]);
  }
}

// ---- 5: per-node mean; one wave/node, 4 ch/lane, degree-loop unrolled x8 ----
__global__ __launch_bounds__(256) void k_aggr(const u16* __restrict__ xb,
    const int* __restrict__ offsets, const int* __restrict__ sorted_src,
    u16* __restrict__ aggr, int n_nodes){
  int wave = threadIdx.x >> 6, lane = threadIdx.x & 63;
  int node = blockIdx.x*4 + wave;
  if(node >= n_nodes) return;
  int b0 = offsets[node], b1 = offsets[node+1];
  const u16* xc = xb + lane*4;
  float s0=0.f, s1=0.f, s2=0.f, s3=0.f;
  int i = b0;
  for(; i+8 <= b1; i+=8){
    int idx[8];
    #pragma unroll
    for(int u=0;u<8;u++) idx[u] = sorted_src[i+u];
    ushort4 v[8];
    #pragma unroll
    for(int u=0;u<8;u++) v[u] = *(const ushort4*)(xc + (size_t)idx[u]*DIM);
    #pragma unroll
    for(int u=0;u<8;u++){
      s0 += bf2f(v[u].x); s1 += bf2f(v[u].y); s2 += bf2f(v[u].z); s3 += bf2f(v[u].w);
    }
  }
  for(; i < b1; i++){
    int sn = sorted_src[i];
    ushort4 v = *(const ushort4*)(xc + (size_t)sn*DIM);
    s0 += bf2f(v.x); s1 += bf2f(v.y); s2 += bf2f(v.z); s3 += bf2f(v.w);
  }
  int deg = b1 - b0;
  float inv = 1.0f / (float)(deg > 1 ? deg : 1);
  ushort4 o;
  o.x = f2bf(s0*inv); o.y = f2bf(s1*inv); o.z = f2bf(s2*inv); o.w = f2bf(s3*inv);
  *(ushort4*)(aggr + (size_t)node*DIM + lane*4) = o;
}

// ---- 6: out = aggr @ Wl^T + x @ Wr^T + b  (MFMA 16x16x32 bf16) ----
// Block = 4 waves covering the SAME 5 M-tiles, 4 DIFFERENT 32-col groups
// -> A-loads coincide across waves (L1/L2 hits), L3 A-traffic /4.
// Per wave: B-frags for 32 cols x K=512 (128 VGPRs) loaded once; then
// 5 tiles x (16 independent A-loads + 32 MFMAs + 8 stores).
__global__ __launch_bounds__(256, 2) void k_gemm(const u16* __restrict__ aggr,
    const u16* __restrict__ xb, const u16* __restrict__ Wcat, const float* __restrict__ br,
    float* __restrict__ out, int Mtiles){
  int wave = threadIdx.x >> 6, lane = threadIdx.x & 63;
  int quad = lane >> 4, l16 = lane & 15;
  int half = blockIdx.x & 1;             // cols [half*128, half*128+128)
  int mb   = blockIdx.x >> 1;            // 5 M-tiles per block
  int colbase = half*128 + wave*32;

  const u16* wbase = Wcat + (size_t)(colbase + l16)*KCAT + quad*8;
  bf16x8 B[2][16];
  #pragma unroll
  for(int ct=0; ct<2; ct++)
    #pragma unroll
    for(int kt=0; kt<16; kt++)
      B[ct][kt] = *(const bf16x8*)(wbase + (size_t)ct*16*KCAT + kt*32);

  int col0 = colbase + l16, col1 = col0 + 16;
  float bi0 = br[col0], bi1 = br[col1];

  #pragma unroll
  for(int tt=0; tt<5; tt++){
    int mt = mb*5 + tt;
    if (mt >= Mtiles) break;
    const u16* arowA = aggr + (size_t)(mt*16 + l16)*DIM + quad*8;
    const u16* arowX = xb   + (size_t)(mt*16 + l16)*DIM + quad*8;
    f32x4 acc0 = {0.f,0.f,0.f,0.f}, acc1 = {0.f,0.f,0.f,0.f};
    #pragma unroll
    for(int kt=0; kt<8; kt++){
      bf16x8 a = *(const bf16x8*)(arowA + kt*32);
      acc0 = __builtin_amdgcn_mfma_f32_16x16x32_bf16(a, B[0][kt], acc0, 0, 0, 0);
      acc1 = __builtin_amdgcn_mfma_f32_16x16x32_bf16(a, B[1][kt], acc1, 0, 0, 0);
    }
    #pragma unroll
    for(int kt=0; kt<8; kt++){
      bf16x8 a = *(const bf16x8*)(arowX + kt*32);
      acc0 = __builtin_amdgcn_mfma_f32_16x16x32_bf16(a, B[0][kt+8], acc0, 0, 0, 0);
      acc1 = __builtin_amdgcn_mfma_f32_16x16x32_bf16(a, B[1][kt+8], acc1, 0, 0, 0);
    }
    size_t base = (size_t)(mt*16 + quad*4)*DIM;
    #pragma unroll
    for(int r=0;r<4;r++){
      out[base + (size_t)r*DIM + col0] = acc0[r] + bi0;
      out[base + (size_t)r*DIM + col1] = acc1[r] + bi1;
    }
  }
}

extern "C" void kernel_launch(void* const* d_in, const int* in_sizes, int n_in,
                              void* d_out, int out_size, void* d_ws, size_t ws_size,
                              hipStream_t stream){
  const float* x  = (const float*)d_in[0];
  const int*   ei = (const int*)d_in[1];
  const float* Wl = (const float*)d_in[2];
  const float* Wr = (const float*)d_in[3];
  const float* br = (const float*)d_in[4];
  float* out = (float*)d_out;
  int n_nodes = in_sizes[0] / DIM;   // 20000
  int E = in_sizes[1] / 2;           // 320000
  const int* src = ei;
  const int* dst = ei + E;

  // workspace layout (16B aligned sections): ~22.3 MB
  int* counts  = (int*)d_ws;                   // [n]
  int* offsets = counts + n_nodes;             // [n+1] (padded to n+8)
  int* cursor  = offsets + (n_nodes + 8);      // [n]
  int* sorted  = cursor + n_nodes;             // [E]
  u16* xb      = (u16*)(sorted + E);           // [n*DIM] bf16
  u16* aggr    = xb + (size_t)n_nodes*DIM;     // [n*DIM] bf16
  u16* Wcat    = aggr + (size_t)n_nodes*DIM;   // [256*512] bf16: [Wl | Wr] per col

  int nX4 = n_nodes*DIM/4, nW4 = DIM*DIM/4;
  int E4 = E >> 2;
  int hist_blocks = ((E4+255)>>8) + ((2*nW4+255)>>8);
  int scat_blocks = ((E4+255)>>8) + ((nX4+255)>>8);
  int Mtiles = n_nodes >> 4;                   // 1250
  int gemm_blocks = ((Mtiles + 4)/5) * 2;      // 500

  hipLaunchKernelGGL(k_zero,         dim3((n_nodes+255)/256), dim3(256), 0, stream, counts, n_nodes);
  hipLaunchKernelGGL(k_hist_cvtw,    dim3(hist_blocks),       dim3(256), 0, stream,
                     dst, E, counts, Wl, Wr, Wcat, nW4);
  hipLaunchKernelGGL(k_scan,         dim3(1),                 dim3(1024),0, stream,
                     counts, n_nodes, offsets, cursor);
  hipLaunchKernelGGL(k_scatter_cvtx, dim3(scat_blocks),       dim3(256), 0, stream,
                     src, dst, E, cursor, sorted, x, xb, nX4);
  hipLaunchKernelGGL(k_aggr,         dim3((n_nodes+3)/4),     dim3(256), 0, stream,
                     xb, offsets, sorted, aggr, n_nodes);
  hipLaunchKernelGGL(k_gemm,         dim3(gemm_blocks),       dim3(256), 0, stream,
                     aggr, xb, Wcat, br, out, Mtiles);
}